// Round 4
// baseline (818.751 us; speedup 1.0000x reference)
//
#include <hip/hip_runtime.h>
#include <hip/hip_bf16.h>

// SymbioticBasisRefinement — folded-Q formulation.
//   KT[e][a] = sum_d basis[a][d] Wk[e][d] + bk[e]
//   P[d][a]  = scale * sum_e Wq[e][d] KT[e][a]             (scale folded)
//   c[a]     = scale * sum_e bq[e]  KT[e][a]
//   attn[r][a] = x[r]·P[:,a] + c[a]  → softmax → x_clean = w·basis, entropy.
// Main kernel: 256 blocks x 256 thr, wave-local (NO inter-wave barriers),
// lane=(row*4+grp), 16 f32 acc/lane, x staged per-wave in LDS, P/basis
// multicast dwordx4 double-buffered. Explicit lgkmcnt(0) drains guard every
// cross-lane LDS exchange (per-lane alias analysis can't see those deps).
// x loads / out stores non-temporal to keep P+basis L2-resident.
// Outer chunk loops unroll(disable)d: GEMM16_CORE ~12KB; outer unrolling
// would blow the 32KB I-cache.

typedef float f32x4 __attribute__((ext_vector_type(4)));

#define DIMD 1024
#define NA 64
#define NROWS 16384
#define SCALE 0.03125f

// drain LDS ops + compiler memory fence: makes cross-lane ds_write->ds_read safe
#define WAVE_LGKM() asm volatile("s_waitcnt lgkmcnt(0)" ::: "memory")

// ---- shared inner GEMM template pieces -------------------------------------
// expects: f32x4 vx[16]; float acc[16]; const float* B (k-major, stride NA, +g*16)
#define LOADPB(DST, K4) { \
  _Pragma("unroll") \
  for (int kk_ = 0; kk_ < 4; kk_++) { \
    _Pragma("unroll") \
    for (int q_ = 0; q_ < 4; q_++) \
      DST[kk_*4+q_] = *(const f32x4*)&B[(size_t)((K4)*4+kk_)*NA + q_*4]; } }

#define COMPUTE(BUF, K4) { \
  _Pragma("unroll") \
  for (int kk_ = 0; kk_ < 4; kk_++) { \
    _Pragma("unroll") \
    for (int q_ = 0; q_ < 4; q_++) { \
      _Pragma("unroll") \
      for (int jj_ = 0; jj_ < 4; jj_++) \
        acc[q_*4+jj_] += vx[K4][kk_] * BUF[kk_*4+q_][jj_]; } } }

#define GEMM16_CORE() { \
  LOADPB(pbA, 0) \
  _Pragma("unroll") \
  for (int k4_ = 0; k4_ < 16; k4_ += 2) { \
    LOADPB(pbB, k4_+1) \
    COMPUTE(pbA, k4_) \
    if (k4_+2 < 16) LOADPB(pbA, k4_+2) \
    COMPUTE(pbB, k4_+1) \
  } }

// ---- init: basisT transpose, KT=bk, P=0, c=0, entropy slot=0 ---------------
__global__ void k_init(const float* __restrict__ basis, const float* __restrict__ bk,
                       float* __restrict__ ws, float* __restrict__ ent) {
  __shared__ float Ts[64][65];
  int b = blockIdx.x, t = threadIdx.x;
  if (b < 16) {                      // basisT tile: d0 = b*64
    int d0 = b * 64;
    #pragma unroll 4
    for (int i = 0; i < 16; i++) { int idx = i*256 + t; int a = idx >> 6, dd = idx & 63;
      Ts[dd][a] = basis[(size_t)a*DIMD + d0 + dd]; }
    __syncthreads();
    float* basisT = ws;
    #pragma unroll 4
    for (int i = 0; i < 16; i++) { int idx = i*256 + t; int dd = idx >> 6, a = idx & 63;
      basisT[(size_t)(d0 + dd)*NA + a] = Ts[dd][a]; }
  } else if (b < 32) {               // KT init = bk[e]
    float* KT = ws + 65536;
    int base = (b - 16) * 4096;
    #pragma unroll 4
    for (int i = 0; i < 16; i++) { int idx = base + i*256 + t; KT[idx] = bk[idx >> 6]; }
  } else if (b < 48) {               // P zero
    float* P = ws + 131072;
    int base = (b - 32) * 4096;
    #pragma unroll 4
    for (int i = 0; i < 16; i++) P[base + i*256 + t] = 0.0f;
  } else {                           // c zero + entropy slot zero
    float* c = ws + 196608;
    if (t < 64) c[t] = 0.0f;
    if (t == 64) *ent = 0.0f;
  }
}

// ---- KT[e][a] += sum_{d in slice} Wk[e][d] * basisT[d][a] ------------------
__global__ __launch_bounds__(256, 1) void k_KT(const float* __restrict__ Wk,
    const float* __restrict__ basisT, float* __restrict__ KT) {
  __shared__ __align__(16) float S[4][16][68];
  int t = threadIdx.x, lane = t & 63, wave = t >> 6, r = lane >> 2, g = lane & 3;
  int e0 = blockIdx.x * 64 + wave * 16;
  int d0 = blockIdx.y * 64;
  const float* src = Wk + (size_t)e0 * DIMD + d0;
  #pragma unroll
  for (int p = 0; p < 4; p++) { int flat = p*256 + lane*4; int rl = flat >> 6, kl = flat & 63;
    *(f32x4*)&S[wave][rl][kl] = *(const f32x4*)&src[(size_t)rl*DIMD + kl]; }
  WAVE_LGKM();
  f32x4 vx[16];
  #pragma unroll
  for (int q = 0; q < 16; q++) vx[q] = *(const f32x4*)&S[wave][r][q*4];
  float acc[16];
  #pragma unroll
  for (int i = 0; i < 16; i++) acc[i] = 0.0f;
  const float* B = basisT + (size_t)d0 * NA + g * 16;
  f32x4 pbA[16], pbB[16];
  GEMM16_CORE()
  float* dst = KT + (size_t)(e0 + r) * NA + g * 16;
  #pragma unroll
  for (int aa = 0; aa < 16; aa++) atomicAdd(&dst[aa], acc[aa]);
}

// ---- P[d][a] += scale * sum_{e in slice} Wq[e][d] * KT[e][a]  (+ c fold) ---
__global__ __launch_bounds__(256, 1) void k_P(const float* __restrict__ Wq,
    const float* __restrict__ KT, const float* __restrict__ bq,
    float* __restrict__ P, float* __restrict__ c) {
  int t = threadIdx.x;
  if (blockIdx.x == 16) {            // c partials: c[a] += scale*sum_{e slice} bq[e]KT[e][a]
    int e0 = blockIdx.y * 64;
    if (t < 64) {
      float p = 0.0f;
      for (int e = e0; e < e0 + 64; e++) p += bq[e] * KT[(size_t)e * NA + t];
      atomicAdd(&c[t], SCALE * p);
    }
    return;
  }
  __shared__ __align__(16) float S[4][16][68];   // S[wave][d_local][e_local]
  int lane = t & 63, wave = t >> 6, r = lane >> 2, g = lane & 3;
  int d0 = blockIdx.x * 64 + wave * 16;          // wave's 16 d-rows
  int e0 = blockIdx.y * 64;
  // stage with transpose: lane l reads Wq[e0+l][d0 + 0..15]
  #pragma unroll
  for (int q = 0; q < 4; q++) {
    f32x4 v = *(const f32x4*)&Wq[(size_t)(e0 + lane)*DIMD + d0 + q*4];
    #pragma unroll
    for (int jj = 0; jj < 4; jj++) S[wave][q*4+jj][lane] = v[jj];
  }
  WAVE_LGKM();
  f32x4 vx[16];
  #pragma unroll
  for (int q = 0; q < 16; q++) vx[q] = *(const f32x4*)&S[wave][r][q*4];
  float acc[16];
  #pragma unroll
  for (int i = 0; i < 16; i++) acc[i] = 0.0f;
  const float* B = KT + (size_t)e0 * NA + g * 16;
  f32x4 pbA[16], pbB[16];
  GEMM16_CORE()
  float* dst = P + (size_t)(d0 + r) * NA + g * 16;
  #pragma unroll
  for (int aa = 0; aa < 16; aa++) atomicAdd(&dst[aa], SCALE * acc[aa]);
}

// ---- main fused kernel ------------------------------------------------------
__global__ __launch_bounds__(256, 2) void k_main(const float* __restrict__ x,
    const float* __restrict__ basis, const float* __restrict__ P,
    const float* __restrict__ cvec, float* __restrict__ out, float* __restrict__ ent) {
  __shared__ __align__(16) float S[4][16][68];     // per-wave x chunk, later w
  int t = threadIdx.x, lane = t & 63, wave = t >> 6, r = lane >> 2, g = lane & 3;
  int rowb = blockIdx.x * 64 + wave * 16;          // wave's first row
  const float* xw = x + (size_t)rowb * DIMD;

  float acc[16];
  #pragma unroll
  for (int i = 0; i < 16; i++) acc[i] = cvec[g*16 + i];

  // prologue: chunk 0 into regs (non-temporal: x is stream-once)
  f32x4 gx[4];
  #pragma unroll
  for (int p = 0; p < 4; p++) { int flat = p*256 + lane*4; int rl = flat >> 6, kl = flat & 63;
    gx[p] = __builtin_nontemporal_load((const f32x4*)&xw[(size_t)rl*DIMD + kl]); }

  // ---- phase 1: attn = x·P + c (16 chunks of 64 k) ----
  #pragma clang loop unroll(disable)
  for (int cc = 0; cc < 16; cc++) {
    #pragma unroll
    for (int p = 0; p < 4; p++) { int flat = p*256 + lane*4; int rl = flat >> 6, kl = flat & 63;
      *(f32x4*)&S[wave][rl][kl] = gx[p]; }
    if (cc < 15) {
      #pragma unroll
      for (int p = 0; p < 4; p++) { int flat = p*256 + lane*4; int rl = flat >> 6, kl = flat & 63;
        gx[p] = __builtin_nontemporal_load((const f32x4*)&xw[(size_t)rl*DIMD + (cc+1)*64 + kl]); }
    }
    WAVE_LGKM();                       // cross-lane: x chunk written by all lanes
    f32x4 vx[16];
    #pragma unroll
    for (int q = 0; q < 16; q++) vx[q] = *(const f32x4*)&S[wave][r][q*4];
    const float* B = P + (size_t)cc * 64 * NA + g * 16;
    f32x4 pbA[16], pbB[16];
    GEMM16_CORE()
  }

  // ---- phase 2: quad-local softmax + entropy ----
  float m = acc[0];
  #pragma unroll
  for (int i = 1; i < 16; i++) m = fmaxf(m, acc[i]);
  m = fmaxf(m, __shfl_xor(m, 1, 64));
  m = fmaxf(m, __shfl_xor(m, 2, 64));
  float w[16]; float ssum = 0.0f;
  #pragma unroll
  for (int i = 0; i < 16; i++) { w[i] = __expf(acc[i] - m); ssum += w[i]; }
  ssum += __shfl_xor(ssum, 1, 64);
  ssum += __shfl_xor(ssum, 2, 64);
  float inv = 1.0f / ssum;
  float entl = 0.0f;
  #pragma unroll
  for (int i = 0; i < 16; i++) { w[i] *= inv; entl += w[i] * __logf(w[i] + 1e-6f); }
  #pragma unroll
  for (int m2 = 1; m2 < 64; m2 <<= 1) entl += __shfl_xor(entl, m2, 64);
  if (lane == 0) atomicAdd(ent, entl * (-1.0f / 16384.0f));

  // write w to wave-local LDS (reuse S), read back full row per lane
  #pragma unroll
  for (int q = 0; q < 4; q++) {
    f32x4 v; v[0] = w[q*4]; v[1] = w[q*4+1]; v[2] = w[q*4+2]; v[3] = w[q*4+3];
    *(f32x4*)&S[wave][r][g*16 + q*4] = v;
  }
  WAVE_LGKM();                         // cross-lane: row weights from 4 lanes
  f32x4 vw[16];
  #pragma unroll
  for (int q = 0; q < 16; q++) vw[q] = *(const f32x4*)&S[wave][r][q*4];

  // ---- phase 3: x_clean = w·basis (16 chunks of 64 d; lane owns 16 d) ----
  size_t orow = (size_t)(rowb + r) * DIMD;
  #pragma clang loop unroll(disable)
  for (int dc = 0; dc < 16; dc++) {
    const float* Bb = basis + (size_t)dc * 64 + g * 16;   // + a*DIMD + q*4
    f32x4 vb[8][4];
    #pragma unroll
    for (int i = 0; i < 8; i++)
      #pragma unroll
      for (int q = 0; q < 4; q++) vb[i][q] = *(const f32x4*)&Bb[(size_t)i*DIMD + q*4];
    float accO[16];
    #pragma unroll
    for (int i = 0; i < 16; i++) accO[i] = 0.0f;
    #pragma unroll
    for (int a = 0; a < 64; a++) {
      float wa = vw[a >> 2][a & 3];
      #pragma unroll
      for (int q = 0; q < 4; q++)
        #pragma unroll
        for (int jj = 0; jj < 4; jj++)
          accO[q*4+jj] += wa * vb[a & 7][q][jj];
      if (a < 56) {
        #pragma unroll
        for (int q = 0; q < 4; q++)
          vb[a & 7][q] = *(const f32x4*)&Bb[(size_t)(a + 8)*DIMD + q*4];
      }
    }
    #pragma unroll
    for (int q = 0; q < 4; q++) {
      f32x4 v; v[0] = accO[q*4]; v[1] = accO[q*4+1]; v[2] = accO[q*4+2]; v[3] = accO[q*4+3];
      __builtin_nontemporal_store(v, (f32x4*)&out[orow + dc*64 + g*16 + q*4]);
    }
  }
}

extern "C" void kernel_launch(void* const* d_in, const int* in_sizes, int n_in,
                              void* d_out, int out_size, void* d_ws, size_t ws_size,
                              hipStream_t stream) {
  (void)in_sizes; (void)n_in; (void)out_size; (void)ws_size;
  const float* x     = (const float*)d_in[0];
  const float* basis = (const float*)d_in[1];
  const float* Wq    = (const float*)d_in[2];
  const float* bq    = (const float*)d_in[3];
  const float* Wk    = (const float*)d_in[4];
  const float* bk    = (const float*)d_in[5];
  float* out = (float*)d_out;
  float* ws  = (float*)d_ws;
  float* basisT = ws;              // [1024][64]
  float* KT     = ws + 65536;      // [1024][64]  K^T (incl. bk)
  float* P      = ws + 131072;     // [1024][64]  scale folded
  float* c      = ws + 196608;     // [64]        scale folded
  float* ent    = out + 16777216;  // entropy slot

  k_init<<<49, 256, 0, stream>>>(basis, bk, ws, ent);
  k_KT<<<dim3(16, 16), 256, 0, stream>>>(Wk, basisT, KT);
  k_P<<<dim3(17, 16), 256, 0, stream>>>(Wq, KT, bq, P, c);
  k_main<<<256, 256, 0, stream>>>(x, basis, P, c, out, ent);
}

// Round 7
// 246.363 us; speedup vs baseline: 3.3234x; 3.3234x over previous
//
#include <hip/hip_runtime.h>
#include <hip/hip_bf16.h>

// SymbioticBasisRefinement v3.1 — folded-Q + R4C4 register tile.
//   KT[e][a] = sum_d Wk[e][d] basisT[d][a] + bk[e]
//   P[d][a]  = SCALE * sum_e Wq[e][d] KT[e][a]
//   c[a]     = SCALE * sum_e bq[e]  KT[e][a]
//   attn = x·P + c -> row softmax -> x_clean = w·basis, entropy.
//
// v1 post-mortem: compiler collapsed register double-buffer (VGPR=124),
// serializing L2 loads -> 560us @ VALUBusy 6%. v2 paper-analysis: R1C4 tile
// over-demands the per-CU LDS pipe 5:2. v3: R4C4 tile (64 FMA per 8 b128
// reads -> LDS:VALU balanced at 4 waves/CU), 64-thr single-wave blocks,
// 1024 blocks. v3.1: overlay Ws onto Xs (phase-disjoint) -> 20.7KB LDS ->
// 7 blocks/CU (was 6).

typedef float f32x4 __attribute__((ext_vector_type(4)));

#define DIMD 1024
#define NA 64
#define SCALE 0.03125f

// R4C4 inner chunk: 16 k4-steps; per k4: 4 xv + 4 bv b128 reads, 64 FMA instr.
// Uses names: Bs[64][64], r4, g, acc0..acc3. XA = A-side LDS array [16][68].
#define GEMM_CHUNK(XA) { \
  _Pragma("unroll") \
  for (int k4 = 0; k4 < 16; k4++) { \
    f32x4 xv0 = *(const f32x4*)&XA[r4*4+0][k4*4]; \
    f32x4 xv1 = *(const f32x4*)&XA[r4*4+1][k4*4]; \
    f32x4 xv2 = *(const f32x4*)&XA[r4*4+2][k4*4]; \
    f32x4 xv3 = *(const f32x4*)&XA[r4*4+3][k4*4]; \
    _Pragma("unroll") \
    for (int kk = 0; kk < 4; kk++) { \
      f32x4 bv = *(const f32x4*)&Bs[k4*4+kk][g*4]; \
      _Pragma("unroll") \
      for (int j = 0; j < 4; j++) { \
        acc0[j] += xv0[kk]*bv[j]; \
        acc1[j] += xv1[kk]*bv[j]; \
        acc2[j] += xv2[kk]*bv[j]; \
        acc3[j] += xv3[kk]*bv[j]; } } } }

// ---- init: basisT transpose, KT=bk, P=0, c=0, entropy=0 --------------------
__global__ void k_init(const float* __restrict__ basis, const float* __restrict__ bk,
                       float* __restrict__ ws, float* __restrict__ ent) {
  __shared__ float Ts[64][65];
  int b = blockIdx.x, t = threadIdx.x;
  if (b < 16) {                      // basisT tile: d0 = b*64
    int d0 = b * 64;
    #pragma unroll 4
    for (int i = 0; i < 16; i++) { int idx = i*256 + t; int a = idx >> 6, dd = idx & 63;
      Ts[dd][a] = basis[(size_t)a*DIMD + d0 + dd]; }
    __syncthreads();
    float* basisT = ws;
    #pragma unroll 4
    for (int i = 0; i < 16; i++) { int idx = i*256 + t; int dd = idx >> 6, a = idx & 63;
      basisT[(size_t)(d0 + dd)*NA + a] = Ts[dd][a]; }
  } else if (b < 32) {               // KT init = bk[e]
    float* KT = ws + 65536;
    int base = (b - 16) * 4096;
    #pragma unroll 4
    for (int i = 0; i < 16; i++) { int idx = base + i*256 + t; KT[idx] = bk[idx >> 6]; }
  } else if (b < 48) {               // P zero
    float* P = ws + 131072;
    int base = (b - 32) * 4096;
    #pragma unroll 4
    for (int i = 0; i < 16; i++) P[base + i*256 + t] = 0.0f;
  } else {                           // c zero + entropy zero
    float* c = ws + 196608;
    if (t < 64) c[t] = 0.0f;
    if (t == 64) *ent = 0.0f;
  }
}

// ---- KT[e][a] += sum_{d slice} Wk[e][d]*basisT[d][a]  (split-K x4) ---------
__global__ __launch_bounds__(64) void k_KT(const float* __restrict__ Wk,
    const float* __restrict__ basisT, float* __restrict__ KT) {
  __shared__ __align__(16) float Bs[64][64];
  __shared__ __align__(16) float Xs[16][68];
  int t = threadIdx.x, r4 = t >> 4, g = t & 15;
  int e0 = blockIdx.x * 16, c0 = blockIdx.y * 4;
  f32x4 acc0 = {0,0,0,0}, acc1 = {0,0,0,0}, acc2 = {0,0,0,0}, acc3 = {0,0,0,0};
  #pragma clang loop unroll(disable)
  for (int cc = c0; cc < c0 + 4; cc++) {
    #pragma unroll
    for (int i = 0; i < 4; i++)
      *(f32x4*)&Xs[i*4+r4][g*4] =
          *(const f32x4*)&Wk[(size_t)(e0 + i*4 + r4)*DIMD + cc*64 + g*4];
    #pragma unroll
    for (int i = 0; i < 16; i++)
      *(f32x4*)&Bs[i*4+r4][g*4] =
          *(const f32x4*)&basisT[(size_t)(cc*64 + i*4 + r4)*NA + g*4];
    __syncthreads();
    GEMM_CHUNK(Xs)
    __syncthreads();
  }
  #pragma unroll
  for (int j = 0; j < 4; j++) {
    atomicAdd(&KT[(size_t)(e0 + r4*4 + 0)*NA + g*4 + j], acc0[j]);
    atomicAdd(&KT[(size_t)(e0 + r4*4 + 1)*NA + g*4 + j], acc1[j]);
    atomicAdd(&KT[(size_t)(e0 + r4*4 + 2)*NA + g*4 + j], acc2[j]);
    atomicAdd(&KT[(size_t)(e0 + r4*4 + 3)*NA + g*4 + j], acc3[j]);
  }
}

// ---- P[d][a] += SCALE*sum_{e slice} Wq[e][d]*KT[e][a]; block x=64: c -------
__global__ __launch_bounds__(64) void k_P(const float* __restrict__ Wq,
    const float* __restrict__ KT, const float* __restrict__ bq,
    float* __restrict__ P, float* __restrict__ c) {
  int t = threadIdx.x;
  if (blockIdx.x == 64) {            // c[a] = SCALE * sum_e bq[e]*KT[e][a]
    if (blockIdx.y != 0) return;
    float s = 0.0f;
    for (int e = 0; e < DIMD; e++) s += bq[e] * KT[(size_t)e*NA + t];
    c[t] = SCALE * s;
    return;
  }
  __shared__ __align__(16) float Bs[64][64];
  __shared__ __align__(16) float Xs[16][68];
  int r4 = t >> 4, g = t & 15;
  int d0 = blockIdx.x * 16, c0 = blockIdx.y * 4;
  f32x4 acc0 = {0,0,0,0}, acc1 = {0,0,0,0}, acc2 = {0,0,0,0}, acc3 = {0,0,0,0};
  #pragma clang loop unroll(disable)
  for (int cc = c0; cc < c0 + 4; cc++) {
    // stage Wq transposed: Xs[d_local][e_local]
    #pragma unroll
    for (int i = 0; i < 4; i++) {
      int seg = i*64 + t; int el = seg >> 2, dq = seg & 3;
      f32x4 v = *(const f32x4*)&Wq[(size_t)(cc*64 + el)*DIMD + d0 + dq*4];
      Xs[dq*4+0][el] = v[0]; Xs[dq*4+1][el] = v[1];
      Xs[dq*4+2][el] = v[2]; Xs[dq*4+3][el] = v[3];
    }
    #pragma unroll
    for (int i = 0; i < 16; i++)
      *(f32x4*)&Bs[i*4+r4][g*4] =
          *(const f32x4*)&KT[(size_t)(cc*64 + i*4 + r4)*NA + g*4];
    __syncthreads();
    GEMM_CHUNK(Xs)
    __syncthreads();
  }
  #pragma unroll
  for (int j = 0; j < 4; j++) {
    atomicAdd(&P[(size_t)(d0 + r4*4 + 0)*NA + g*4 + j], SCALE*acc0[j]);
    atomicAdd(&P[(size_t)(d0 + r4*4 + 1)*NA + g*4 + j], SCALE*acc1[j]);
    atomicAdd(&P[(size_t)(d0 + r4*4 + 2)*NA + g*4 + j], SCALE*acc2[j]);
    atomicAdd(&P[(size_t)(d0 + r4*4 + 3)*NA + g*4 + j], SCALE*acc3[j]);
  }
}

// ---- main fused kernel: 1024 blocks x 64 thr, 16 rows/block ----------------
// LDS = Bs 16KB + Xs 4.35KB = 20.7KB -> 7 blocks/CU. Xs doubles as the
// softmax-weight buffer in phase 3 (phase-disjoint lifetimes).
__global__ __launch_bounds__(64) void k_main(const float* __restrict__ x,
    const float* __restrict__ basis, const float* __restrict__ P,
    const float* __restrict__ cvec, float* __restrict__ out, float* __restrict__ ent) {
  __shared__ __align__(16) float Bs[64][64];
  __shared__ __align__(16) float Xs[16][68];
  int t = threadIdx.x, r4 = t >> 4, g = t & 15;
  int rowb = blockIdx.x * 16;

  f32x4 cv = *(const f32x4*)&cvec[g*4];
  f32x4 acc0 = cv, acc1 = cv, acc2 = cv, acc3 = cv;

  // prefetch x chunk 0 (thread's 4 staging segments)
  f32x4 gx[4];
  #pragma unroll
  for (int i = 0; i < 4; i++)
    gx[i] = __builtin_nontemporal_load(
        (const f32x4*)&x[(size_t)(rowb + i*4 + r4)*DIMD + g*4]);

  // ---- phase 1: attn = x·P + c (16 k-chunks of 64) ----
  #pragma clang loop unroll(disable)
  for (int cc = 0; cc < 16; cc++) {
    #pragma unroll
    for (int i = 0; i < 4; i++) *(f32x4*)&Xs[i*4+r4][g*4] = gx[i];
    #pragma unroll
    for (int i = 0; i < 16; i++)
      *(f32x4*)&Bs[i*4+r4][g*4] =
          *(const f32x4*)&P[(size_t)(cc*64 + i*4 + r4)*NA + g*4];
    __syncthreads();
    if (cc < 15) {
      #pragma unroll
      for (int i = 0; i < 4; i++)
        gx[i] = __builtin_nontemporal_load(
            (const f32x4*)&x[(size_t)(rowb + i*4 + r4)*DIMD + (cc+1)*64 + g*4]);
    }
    GEMM_CHUNK(Xs)
    __syncthreads();
  }

  // ---- phase 2: row softmax over 16-lane groups (lane bits 0-3) ----
  float m0 = fmaxf(fmaxf(acc0[0],acc0[1]), fmaxf(acc0[2],acc0[3]));
  float m1 = fmaxf(fmaxf(acc1[0],acc1[1]), fmaxf(acc1[2],acc1[3]));
  float m2 = fmaxf(fmaxf(acc2[0],acc2[1]), fmaxf(acc2[2],acc2[3]));
  float m3 = fmaxf(fmaxf(acc3[0],acc3[1]), fmaxf(acc3[2],acc3[3]));
  #pragma unroll
  for (int s = 1; s < 16; s <<= 1) {
    m0 = fmaxf(m0, __shfl_xor(m0, s, 64));
    m1 = fmaxf(m1, __shfl_xor(m1, s, 64));
    m2 = fmaxf(m2, __shfl_xor(m2, s, 64));
    m3 = fmaxf(m3, __shfl_xor(m3, s, 64));
  }
  f32x4 w0, w1, w2, w3;
  #pragma unroll
  for (int j = 0; j < 4; j++) {
    w0[j] = __expf(acc0[j] - m0); w1[j] = __expf(acc1[j] - m1);
    w2[j] = __expf(acc2[j] - m2); w3[j] = __expf(acc3[j] - m3);
  }
  float s0 = w0[0]+w0[1]+w0[2]+w0[3], s1 = w1[0]+w1[1]+w1[2]+w1[3];
  float s2 = w2[0]+w2[1]+w2[2]+w2[3], s3 = w3[0]+w3[1]+w3[2]+w3[3];
  #pragma unroll
  for (int s = 1; s < 16; s <<= 1) {
    s0 += __shfl_xor(s0, s, 64); s1 += __shfl_xor(s1, s, 64);
    s2 += __shfl_xor(s2, s, 64); s3 += __shfl_xor(s3, s, 64);
  }
  float i0 = 1.0f/s0, i1 = 1.0f/s1, i2 = 1.0f/s2, i3 = 1.0f/s3;
  float e0 = 0.f, e1 = 0.f, e2 = 0.f, e3 = 0.f;
  #pragma unroll
  for (int j = 0; j < 4; j++) {
    w0[j] *= i0; w1[j] *= i1; w2[j] *= i2; w3[j] *= i3;
    e0 += w0[j]*__logf(w0[j]+1e-6f); e1 += w1[j]*__logf(w1[j]+1e-6f);
    e2 += w2[j]*__logf(w2[j]+1e-6f); e3 += w3[j]*__logf(w3[j]+1e-6f);
  }
  #pragma unroll
  for (int s = 1; s < 16; s <<= 1) {
    e0 += __shfl_xor(e0, s, 64); e1 += __shfl_xor(e1, s, 64);
    e2 += __shfl_xor(e2, s, 64); e3 += __shfl_xor(e3, s, 64);
  }
  float eb = e0 + e1 + e2 + e3;           // group-uniform per r4
  eb += __shfl_xor(eb, 16, 64);
  eb += __shfl_xor(eb, 32, 64);           // block total (16 rows)
  if (t == 0) atomicAdd(ent, eb * (-1.0f / 16384.0f));
  // weights into Xs (overlay; x-operand lifetime ended with phase 1)
  *(f32x4*)&Xs[r4*4+0][g*4] = w0;
  *(f32x4*)&Xs[r4*4+1][g*4] = w1;
  *(f32x4*)&Xs[r4*4+2][g*4] = w2;
  *(f32x4*)&Xs[r4*4+3][g*4] = w3;
  // visibility covered by first __syncthreads in phase-3 loop.

  // ---- phase 3: x_clean = w·basis (16 d-chunks of 64; g = dim-group) ----
  #pragma clang loop unroll(disable)
  for (int dc = 0; dc < 16; dc++) {
    #pragma unroll
    for (int i = 0; i < 16; i++)
      *(f32x4*)&Bs[i*4+r4][g*4] =
          *(const f32x4*)&basis[(size_t)(i*4 + r4)*DIMD + dc*64 + g*4];
    __syncthreads();
    {
      f32x4 acc0 = {0,0,0,0}, acc1 = {0,0,0,0}, acc2 = {0,0,0,0}, acc3 = {0,0,0,0};
      GEMM_CHUNK(Xs)
      __builtin_nontemporal_store(acc0,
          (f32x4*)&out[(size_t)(rowb + r4*4 + 0)*DIMD + dc*64 + g*4]);
      __builtin_nontemporal_store(acc1,
          (f32x4*)&out[(size_t)(rowb + r4*4 + 1)*DIMD + dc*64 + g*4]);
      __builtin_nontemporal_store(acc2,
          (f32x4*)&out[(size_t)(rowb + r4*4 + 2)*DIMD + dc*64 + g*4]);
      __builtin_nontemporal_store(acc3,
          (f32x4*)&out[(size_t)(rowb + r4*4 + 3)*DIMD + dc*64 + g*4]);
    }
    __syncthreads();
  }
}

extern "C" void kernel_launch(void* const* d_in, const int* in_sizes, int n_in,
                              void* d_out, int out_size, void* d_ws, size_t ws_size,
                              hipStream_t stream) {
  (void)in_sizes; (void)n_in; (void)out_size; (void)ws_size;
  const float* x     = (const float*)d_in[0];
  const float* basis = (const float*)d_in[1];
  const float* Wq    = (const float*)d_in[2];
  const float* bq    = (const float*)d_in[3];
  const float* Wk    = (const float*)d_in[4];
  const float* bk    = (const float*)d_in[5];
  float* out = (float*)d_out;
  float* ws  = (float*)d_ws;
  float* basisT = ws;              // [1024][64]
  float* KT     = ws + 65536;      // [1024][64]  (pre-init = bk)
  float* P      = ws + 131072;     // [1024][64]  (scale folded, pre-init 0)
  float* c      = ws + 196608;     // [64]        (scale folded)
  float* ent    = out + 16777216;  // entropy slot

  k_init<<<49, 256, 0, stream>>>(basis, bk, ws, ent);
  k_KT<<<dim3(64, 4), 64, 0, stream>>>(Wk, basisT, KT);
  k_P<<<dim3(65, 4), 64, 0, stream>>>(Wq, KT, bq, P, c);
  k_main<<<1024, 64, 0, stream>>>(x, basis, P, c, out, ent);
}